// Round 21
// baseline (128.142 us; speedup 1.0000x reference)
//
#include <hip/hip_runtime.h>
#include <hip/hip_bf16.h>
#include <hip/hip_fp8.h>
#include <limits.h>

#define NUM_NODES 100000
#define OUT_CH 64
#define NUM_EDGES 3200000
#define BROWS 64                     // rows per bucket
#define BSHIFT 6
#define NBUCK 1563                   // ceil(100000/64) raw-row buckets
#define NBUCK_EXT 3125               // spmm grid covers out rows for any minv
#define NPBLK 500                    // edge-pass blocks
#define EPB (NUM_EDGES / NPBLK)      // 6400
#define I4PB (EPB / 4)               // 1600
#define CAP 4096                     // per-bucket region capacity (avg 2046, max~2300)
#define CAPSHIFT 12
#define STAGECAP 4096
#define NTRANS 1563                  // transpose blocks
#define FP8_SCALE 256.0f
#define FP8_INV (1.0f / 256.0f)

typedef float v2f __attribute__((ext_vector_type(2)));

__device__ __forceinline__ float fp8_decode_slow(unsigned b) {
    unsigned s = b >> 7, e = (b >> 3) & 0xF, m = b & 7;
    float v = (e == 0) ? ldexpf((float)m, -9) : ldexpf((float)(8 + m), (int)e - 10);
    return s ? -v : v;
}

// ---------- K1: fused [transpose->fp8] || [min + hist + chunk-reserve] ----------
__global__ __launch_bounds__(256) void LINK_62689342652831_mth_kernel(
    const float* __restrict__ W, unsigned char* __restrict__ Wt8,
    const int* __restrict__ rows, int* __restrict__ minp,
    int* __restrict__ gcur, int* __restrict__ cbase) {
    __shared__ float tile[64][65];   // 16640 B
    if (blockIdx.x < NTRANS) {
        int n0 = blockIdx.x * 64;
        int tx = threadIdx.x & 63;
        int ty = threadIdx.x >> 6;
        for (int c = ty; c < 64; c += 4) {
            int n = n0 + tx;
            tile[c][tx] = (n < NUM_NODES) ? W[(size_t)c * NUM_NODES + n] : 0.0f;
        }
        __syncthreads();
        for (int i = ty; i < 64; i += 4) {
            int n = n0 + i;
            if (n < NUM_NODES) {
                __hip_fp8_e4m3 q(FP8_SCALE * tile[tx][i]);
                Wt8[(size_t)n * OUT_CH + tx] = *reinterpret_cast<unsigned char*>(&q);
            }
        }
    } else {
        int blk = blockIdx.x - NTRANS;  // 0..NPBLK-1
        int* h = (int*)tile;            // NBUCK ints
        int* sm = (int*)tile + 2048;    // 4 ints, beyond h
        for (int i = threadIdx.x; i < NBUCK; i += 256) h[i] = 0;
        __syncthreads();
        const int4* r4 = (const int4*)rows;
        int m = INT_MAX;
        for (int i = threadIdx.x; i < I4PB; i += 256) {
            int4 v = r4[blk * I4PB + i];
            m = min(m, min(min(v.x, v.y), min(v.z, v.w)));
            atomicAdd(&h[(unsigned)v.x >> BSHIFT], 1);
            atomicAdd(&h[(unsigned)v.y >> BSHIFT], 1);
            atomicAdd(&h[(unsigned)v.z >> BSHIFT], 1);
            atomicAdd(&h[(unsigned)v.w >> BSHIFT], 1);
        }
        for (int off = 32; off > 0; off >>= 1) m = min(m, __shfl_xor(m, off, 64));
        if ((threadIdx.x & 63) == 0) sm[threadIdx.x >> 6] = m;
        __syncthreads();
        // chunk reservation: one global atomic per non-empty (block,bucket)
        for (int i = threadIdx.x; i < NBUCK; i += 256) {
            int c = h[i];
            if (c) cbase[blk * NBUCK + i] = atomicAdd(&gcur[i], c);
        }
        if (threadIdx.x == 0)
            atomicMin(minp, min(min(sm[0], sm[1]), min(sm[2], sm[3])));
    }
}

// ---------- K2: partition edges into reserved chunks (LDS cursors) ----------
__global__ __launch_bounds__(512) void LINK_62689342652831_part_kernel(
    const int* __restrict__ rows, const int* __restrict__ cols,
    const int* __restrict__ cbase, unsigned int* __restrict__ packed) {
    __shared__ int offs_l[NBUCK];
    __shared__ int lcur[NBUCK];
    int blk = blockIdx.x;
    for (int i = threadIdx.x; i < NBUCK; i += 512) {
        offs_l[i] = (i << CAPSHIFT) + cbase[blk * NBUCK + i];  // garbage iff bucket empty
        lcur[i] = 0;
    }
    __syncthreads();
    const int4* r4 = (const int4*)rows;
    const int4* c4 = (const int4*)cols;
    for (int i = threadIdx.x; i < I4PB; i += 512) {
        int4 rv = r4[blk * I4PB + i];
        int4 cv = c4[blk * I4PB + i];
#pragma unroll
        for (int k = 0; k < 4; ++k) {
            int r = (k == 0) ? rv.x : (k == 1) ? rv.y : (k == 2) ? rv.z : rv.w;
            int c = (k == 0) ? cv.x : (k == 1) ? cv.y : (k == 2) ? cv.z : cv.w;
            int b = (unsigned)r >> BSHIFT;
            int pos = offs_l[b] + atomicAdd(&lcur[b], 1);
            if (pos < ((b + 1) << CAPSHIFT))  // overflow guard (structurally ~never)
                packed[pos] = ((unsigned)(r & (BROWS - 1)) << 17) | (unsigned)c;
        }
    }
}

// ---------- K3: per-bucket counting-sort + fp8 gather SpMM + log_softmax ----------
__global__ __launch_bounds__(256) void LINK_62689342652831_spmm_kernel(
    const unsigned int* __restrict__ packed, const int* __restrict__ gcur,
    const unsigned char* __restrict__ Wt8, const float* __restrict__ bias,
    const int* __restrict__ minp, float* __restrict__ out) {
    __shared__ unsigned int sorted[STAGECAP];
    __shared__ int rhist[BROWS];
    __shared__ int rstart[BROWS + 1];
    __shared__ int rcur[BROWS];

    int lane = threadIdx.x & 63;
    int wid = threadIdx.x >> 6;  // 0..3
    int b = blockIdx.x;
    int minv = *minp;
    if (b * BROWS - minv >= NUM_NODES) return;
    int s = b << CAPSHIFT;
    int n = 0;
    if (b < NBUCK) n = min(gcur[b], CAP);

    // ---- hist phase (uint4 body; s is 16B-aligned) ----
    int nb = n >> 2;
    int tl = nb * 4;
    const uint4* p4 = (const uint4*)(packed + s);

    if (threadIdx.x < BROWS) rhist[threadIdx.x] = 0;
    __syncthreads();
    for (int i = threadIdx.x; i < nb; i += 256) {
        uint4 u = p4[i];
        atomicAdd(&rhist[u.x >> 17], 1);
        atomicAdd(&rhist[u.y >> 17], 1);
        atomicAdd(&rhist[u.z >> 17], 1);
        atomicAdd(&rhist[u.w >> 17], 1);
    }
    if (tl + (int)threadIdx.x < n)
        atomicAdd(&rhist[packed[s + tl + threadIdx.x] >> 17], 1);
    __syncthreads();
    if (threadIdx.x < 64) {
        int c0 = rhist[lane];
        int x0 = c0;
        for (int off = 1; off < 64; off <<= 1) {
            int y0 = __shfl_up(x0, off, 64);
            if (lane >= off) x0 += y0;
        }
        rstart[lane] = x0 - c0;
        rcur[lane] = x0 - c0;
        if (lane == 63) rstart[64] = x0;
    }
    __syncthreads();
    // ---- scatter phase (uint4 body) ----
    for (int i = threadIdx.x; i < nb; i += 256) {
        uint4 u = p4[i];
        sorted[atomicAdd(&rcur[u.x >> 17], 1)] = u.x;
        sorted[atomicAdd(&rcur[u.y >> 17], 1)] = u.y;
        sorted[atomicAdd(&rcur[u.z >> 17], 1)] = u.z;
        sorted[atomicAdd(&rcur[u.w >> 17], 1)] = u.w;
    }
    if (tl + (int)threadIdx.x < n) {
        unsigned int u = packed[s + tl + threadIdx.x];
        sorted[atomicAdd(&rcur[u >> 17], 1)] = u;
    }
    __syncthreads();

    // ---- gather: 16 lanes/edge (1 dword = 4 fp8 ch/lane), 4-deep MLP ----
    const unsigned int* Wt1 = (const unsigned int*)Wt8;  // row = 16 dwords
    int q = lane >> 4;
    int ql = lane & 15;
    float b0 = bias[4 * ql], b1 = bias[4 * ql + 1],
          b2 = bias[4 * ql + 2], b3 = bias[4 * ql + 3];

    for (int r = wid; r < BROWS; r += 4) {
        int gr = b * BROWS + r - minv;
        if (gr < 0 || gr >= NUM_NODES) continue;
        int s0 = rstart[r], e0 = rstart[r + 1];
        v2f a01 = {0.0f, 0.0f}, a23 = {0.0f, 0.0f};
        int i = s0 + q;
        for (; i + 12 < e0; i += 16) {  // 4 independent edges in flight
            unsigned int ua = sorted[i], ub = sorted[i + 4];
            unsigned int uc = sorted[i + 8], ud = sorted[i + 12];
            unsigned int wa = Wt1[(size_t)((ua & 0x1FFFFu) << 4) + ql];
            unsigned int wb = Wt1[(size_t)((ub & 0x1FFFFu) << 4) + ql];
            unsigned int wc = Wt1[(size_t)((uc & 0x1FFFFu) << 4) + ql];
            unsigned int wd = Wt1[(size_t)((ud & 0x1FFFFu) << 4) + ql];
#if __has_builtin(__builtin_amdgcn_cvt_pk_f32_fp8)
            a01 += __builtin_amdgcn_cvt_pk_f32_fp8((int)wa, false);
            a23 += __builtin_amdgcn_cvt_pk_f32_fp8((int)wa, true);
            a01 += __builtin_amdgcn_cvt_pk_f32_fp8((int)wb, false);
            a23 += __builtin_amdgcn_cvt_pk_f32_fp8((int)wb, true);
            a01 += __builtin_amdgcn_cvt_pk_f32_fp8((int)wc, false);
            a23 += __builtin_amdgcn_cvt_pk_f32_fp8((int)wc, true);
            a01 += __builtin_amdgcn_cvt_pk_f32_fp8((int)wd, false);
            a23 += __builtin_amdgcn_cvt_pk_f32_fp8((int)wd, true);
#else
            a01.x += fp8_decode_slow(wa & 0xFF) + fp8_decode_slow(wb & 0xFF)
                   + fp8_decode_slow(wc & 0xFF) + fp8_decode_slow(wd & 0xFF);
            a01.y += fp8_decode_slow((wa >> 8) & 0xFF) + fp8_decode_slow((wb >> 8) & 0xFF)
                   + fp8_decode_slow((wc >> 8) & 0xFF) + fp8_decode_slow((wd >> 8) & 0xFF);
            a23.x += fp8_decode_slow((wa >> 16) & 0xFF) + fp8_decode_slow((wb >> 16) & 0xFF)
                   + fp8_decode_slow((wc >> 16) & 0xFF) + fp8_decode_slow((wd >> 16) & 0xFF);
            a23.y += fp8_decode_slow(wa >> 24) + fp8_decode_slow(wb >> 24)
                   + fp8_decode_slow(wc >> 24) + fp8_decode_slow(wd >> 24);
#endif
        }
        for (; i < e0; i += 4) {
            unsigned int w = Wt1[(size_t)((sorted[i] & 0x1FFFFu) << 4) + ql];
#if __has_builtin(__builtin_amdgcn_cvt_pk_f32_fp8)
            a01 += __builtin_amdgcn_cvt_pk_f32_fp8((int)w, false);
            a23 += __builtin_amdgcn_cvt_pk_f32_fp8((int)w, true);
#else
            a01.x += fp8_decode_slow(w & 0xFF);
            a01.y += fp8_decode_slow((w >> 8) & 0xFF);
            a23.x += fp8_decode_slow((w >> 16) & 0xFF);
            a23.y += fp8_decode_slow(w >> 24);
#endif
        }
        float a0 = a01.x, a1 = a01.y, a2 = a23.x, a3 = a23.y;
        a0 += __shfl_xor(a0, 32, 64); a1 += __shfl_xor(a1, 32, 64);
        a2 += __shfl_xor(a2, 32, 64); a3 += __shfl_xor(a3, 32, 64);
        a0 += __shfl_xor(a0, 16, 64); a1 += __shfl_xor(a1, 16, 64);
        a2 += __shfl_xor(a2, 16, 64); a3 += __shfl_xor(a3, 16, 64);

        float x0 = a0 * FP8_INV + b0, x1 = a1 * FP8_INV + b1;
        float x2 = a2 * FP8_INV + b2, x3 = a3 * FP8_INV + b3;
        float m = fmaxf(fmaxf(x0, x1), fmaxf(x2, x3));
        for (int off = 8; off > 0; off >>= 1) m = fmaxf(m, __shfl_xor(m, off, 64));
        float ssum = __expf(x0 - m) + __expf(x1 - m) + __expf(x2 - m) + __expf(x3 - m);
        for (int off = 8; off > 0; off >>= 1) ssum += __shfl_xor(ssum, off, 64);
        float l = m + __logf(ssum);
        if (lane < 16) {
            float4 o = {x0 - l, x1 - l, x2 - l, x3 - l};
            *(float4*)&out[(size_t)gr * OUT_CH + 4 * ql] = o;
        }
    }
}

// ---------- fallback (round-1 path, direct W) ----------
__global__ void LINK_62689342652831_minf_kernel(const int* __restrict__ rows, int n,
                                                int* __restrict__ minp) {
    int tid = blockIdx.x * blockDim.x + threadIdx.x;
    int stride = gridDim.x * blockDim.x;
    int m = INT_MAX;
    for (int i = tid; i < n; i += stride) m = min(m, rows[i]);
    for (int off = 32; off > 0; off >>= 1) m = min(m, __shfl_xor(m, off, 64));
    if ((threadIdx.x & 63) == 0) atomicMin(minp, m);
}

__global__ void LINK_62689342652831_scatter_kernel(const int* __restrict__ rows,
                                                   const int* __restrict__ cols,
                                                   const float* __restrict__ W,
                                                   const int* __restrict__ minp,
                                                   float* __restrict__ out) {
    int lane = threadIdx.x & 63;
    int gw = (blockIdx.x * blockDim.x + threadIdx.x) >> 6;
    int nw = (gridDim.x * blockDim.x) >> 6;
    int minv = *minp;
    for (int e = gw; e < NUM_EDGES; e += nw) {
        int r = rows[e] - minv;
        int c = cols[e];
        float v = W[(size_t)lane * NUM_NODES + c];
        unsafeAtomicAdd(&out[(size_t)r * 64 + lane], v);
    }
}

__global__ void LINK_62689342652831_logsoftmax_kernel(float* __restrict__ out,
                                                      const float* __restrict__ bias) {
    int lane = threadIdx.x & 63;
    int gw = (blockIdx.x * blockDim.x + threadIdx.x) >> 6;
    int nw = (gridDim.x * blockDim.x) >> 6;
    float b = bias[lane];
    for (int r = gw; r < NUM_NODES; r += nw) {
        float x = out[(size_t)r * 64 + lane] + b;
        float m = x;
        for (int off = 32; off > 0; off >>= 1) m = fmaxf(m, __shfl_xor(m, off, 64));
        float e = expf(x - m);
        float s = e;
        for (int off = 32; off > 0; off >>= 1) s += __shfl_xor(s, off, 64);
        out[(size_t)r * 64 + lane] = x - m - logf(s);
    }
}

extern "C" void kernel_launch(void* const* d_in, const int* in_sizes, int n_in,
                              void* d_out, int out_size, void* d_ws, size_t ws_size,
                              hipStream_t stream) {
    const int* edges = (const int*)d_in[0];
    const int* rows = edges;
    const int* cols = edges + NUM_EDGES;
    const float* W = (const float*)d_in[1];
    const float* bias = (const float*)d_in[2];
    float* out = (float*)d_out;

    // workspace layout
    char* ws = (char*)d_ws;
    const size_t OFF_MIN = 0;                                  // 4 B
    const size_t OFF_GCUR = 1024;                              // NBUCK*4 = 6252 B
    const size_t OFF_CBASE = 16384;                            // 500*1563*4 = 3126000 B
    const size_t OFF_PACKED = 4 * 1024 * 1024;                 // NBUCK*CAP*4 = 25.6 MB
    const size_t OFF_WT8 = OFF_PACKED + (size_t)NBUCK * CAP * 4;
    const size_t need = OFF_WT8 + (size_t)NUM_NODES * OUT_CH;

    int* minp = (int*)(ws + OFF_MIN);
    int* gcur = (int*)(ws + OFF_GCUR);
    int* cbase = (int*)(ws + OFF_CBASE);
    unsigned int* packed = (unsigned int*)(ws + OFF_PACKED);
    unsigned char* Wt8 = (unsigned char*)(ws + OFF_WT8);

    hipMemsetAsync(minp, 0x7f, sizeof(int), stream);

    if (ws_size >= need) {
        hipMemsetAsync(gcur, 0, (size_t)NBUCK * sizeof(int), stream);
        LINK_62689342652831_mth_kernel<<<NTRANS + NPBLK, 256, 0, stream>>>(W, Wt8, rows,
                                                                           minp, gcur, cbase);
        LINK_62689342652831_part_kernel<<<NPBLK, 512, 0, stream>>>(rows, cols, cbase, packed);
        LINK_62689342652831_spmm_kernel<<<NBUCK_EXT, 256, 0, stream>>>(packed, gcur, Wt8,
                                                                       bias, minp, out);
    } else {
        LINK_62689342652831_minf_kernel<<<2048, 256, 0, stream>>>(rows, NUM_EDGES, minp);
        hipMemsetAsync(d_out, 0, (size_t)out_size * sizeof(float), stream);
        LINK_62689342652831_scatter_kernel<<<2048, 256, 0, stream>>>(rows, cols, W, minp, out);
        LINK_62689342652831_logsoftmax_kernel<<<4096, 256, 0, stream>>>(out, bias);
    }
}

// Round 22
// 111.636 us; speedup vs baseline: 1.1479x; 1.1479x over previous
//
#include <hip/hip_runtime.h>
#include <hip/hip_bf16.h>
#include <hip/hip_fp8.h>
#include <limits.h>

#define NUM_NODES 100000
#define OUT_CH 64
#define NUM_EDGES 3200000
#define BROWS 64                     // rows per bucket
#define BSHIFT 6
#define NBUCK 1563                   // ceil(100000/64) raw-row buckets
#define NBUCK_EXT 3125               // spmm grid covers out rows for any minv
#define NPBLK 256                    // edge-pass blocks
#define EPB (NUM_EDGES / NPBLK)      // 12500
#define I4PB (EPB / 4)               // 3125
#define CAP 4096                     // per-bucket region capacity (avg 2046, max~2300)
#define CAPSHIFT 12
#define STAGECAP 4096
#define NTRANS 1563                  // transpose blocks
#define FP8_SCALE 256.0f
#define FP8_INV (1.0f / 256.0f)

typedef float v2f __attribute__((ext_vector_type(2)));

__device__ __forceinline__ float fp8_decode_slow(unsigned b) {
    unsigned s = b >> 7, e = (b >> 3) & 0xF, m = b & 7;
    float v = (e == 0) ? ldexpf((float)m, -9) : ldexpf((float)(8 + m), (int)e - 10);
    return s ? -v : v;
}

// ---------- K0: init (replaces two memsets) ----------
__global__ __launch_bounds__(256) void LINK_62689342652831_init_kernel(
    int* __restrict__ minp, int* __restrict__ gcur) {
    int tid = blockIdx.x * 256 + threadIdx.x;
    if (tid == 0) *minp = INT_MAX;
    for (int i = tid; i < NBUCK; i += gridDim.x * 256) gcur[i] = 0;
}

// ---------- K1: fused [transpose->fp8] || [min + hist + chunk-reserve] ----------
__global__ __launch_bounds__(512) void LINK_62689342652831_mth_kernel(
    const float* __restrict__ W, unsigned char* __restrict__ Wt8,
    const int* __restrict__ rows, int* __restrict__ minp,
    int* __restrict__ gcur, int* __restrict__ cbase) {
    __shared__ float tile[64][65];   // 16640 B
    if (blockIdx.x < NTRANS) {
        int n0 = blockIdx.x * 64;
        int tx = threadIdx.x & 63;
        int ty = threadIdx.x >> 6;   // 0..7
        for (int c = ty; c < 64; c += 8) {
            int n = n0 + tx;
            tile[c][tx] = (n < NUM_NODES) ? W[(size_t)c * NUM_NODES + n] : 0.0f;
        }
        __syncthreads();
        for (int i = ty; i < 64; i += 8) {
            int n = n0 + i;
            if (n < NUM_NODES) {
                __hip_fp8_e4m3 q(FP8_SCALE * tile[tx][i]);
                Wt8[(size_t)n * OUT_CH + tx] = *reinterpret_cast<unsigned char*>(&q);
            }
        }
    } else {
        int blk = blockIdx.x - NTRANS;  // 0..NPBLK-1
        int* h = (int*)tile;            // NBUCK ints
        int* sm = (int*)tile + 2048;    // 8 ints, beyond h
        for (int i = threadIdx.x; i < NBUCK; i += 512) h[i] = 0;
        __syncthreads();
        const int4* r4 = (const int4*)rows;
        int m = INT_MAX;
        for (int i = threadIdx.x; i < I4PB; i += 512) {
            int4 v = r4[blk * I4PB + i];
            m = min(m, min(min(v.x, v.y), min(v.z, v.w)));
            atomicAdd(&h[(unsigned)v.x >> BSHIFT], 1);
            atomicAdd(&h[(unsigned)v.y >> BSHIFT], 1);
            atomicAdd(&h[(unsigned)v.z >> BSHIFT], 1);
            atomicAdd(&h[(unsigned)v.w >> BSHIFT], 1);
        }
        for (int off = 32; off > 0; off >>= 1) m = min(m, __shfl_xor(m, off, 64));
        if ((threadIdx.x & 63) == 0) sm[threadIdx.x >> 6] = m;
        __syncthreads();
        // chunk reservation: one global atomic per non-empty (block,bucket)
        for (int i = threadIdx.x; i < NBUCK; i += 512) {
            int c = h[i];
            if (c) cbase[blk * NBUCK + i] = atomicAdd(&gcur[i], c);
        }
        if (threadIdx.x == 0) {
            int mm = sm[0];
#pragma unroll
            for (int k = 1; k < 8; ++k) mm = min(mm, sm[k]);
            atomicMin(minp, mm);
        }
    }
}

// ---------- K2: partition edges into reserved chunks (LDS cursors) ----------
__global__ __launch_bounds__(512) void LINK_62689342652831_part_kernel(
    const int* __restrict__ rows, const int* __restrict__ cols,
    const int* __restrict__ cbase, unsigned int* __restrict__ packed) {
    __shared__ int offs_l[NBUCK];
    __shared__ int lcur[NBUCK];
    int blk = blockIdx.x;
    for (int i = threadIdx.x; i < NBUCK; i += 512) {
        offs_l[i] = (i << CAPSHIFT) + cbase[blk * NBUCK + i];  // garbage iff bucket empty
        lcur[i] = 0;
    }
    __syncthreads();
    const int4* r4 = (const int4*)rows;
    const int4* c4 = (const int4*)cols;
    for (int i = threadIdx.x; i < I4PB; i += 512) {
        int4 rv = r4[blk * I4PB + i];
        int4 cv = c4[blk * I4PB + i];
#pragma unroll
        for (int k = 0; k < 4; ++k) {
            int r = (k == 0) ? rv.x : (k == 1) ? rv.y : (k == 2) ? rv.z : rv.w;
            int c = (k == 0) ? cv.x : (k == 1) ? cv.y : (k == 2) ? cv.z : cv.w;
            int b = (unsigned)r >> BSHIFT;
            int pos = offs_l[b] + atomicAdd(&lcur[b], 1);
            if (pos < ((b + 1) << CAPSHIFT))  // overflow guard (structurally ~never)
                packed[pos] = ((unsigned)(r & (BROWS - 1)) << 17) | (unsigned)c;
        }
    }
}

// ---------- K3: per-bucket counting-sort + fp8 gather SpMM + log_softmax ----------
__global__ __launch_bounds__(256) void LINK_62689342652831_spmm_kernel(
    const unsigned int* __restrict__ packed, const int* __restrict__ gcur,
    const unsigned char* __restrict__ Wt8, const float* __restrict__ bias,
    const int* __restrict__ minp, float* __restrict__ out) {
    __shared__ unsigned int sorted[STAGECAP];
    __shared__ int rhist[BROWS];
    __shared__ int rstart[BROWS + 1];
    __shared__ int rcur[BROWS];

    int lane = threadIdx.x & 63;
    int wid = threadIdx.x >> 6;  // 0..3
    int b = blockIdx.x;
    int minv = *minp;
    if (b * BROWS - minv >= NUM_NODES) return;
    int s = b << CAPSHIFT;
    int n = 0;
    if (b < NBUCK) n = min(gcur[b], CAP);

    // ---- hist phase (uint4 body; s is 16B-aligned) ----
    int nb = n >> 2;
    int tl = nb * 4;
    const uint4* p4 = (const uint4*)(packed + s);

    if (threadIdx.x < BROWS) rhist[threadIdx.x] = 0;
    __syncthreads();
    for (int i = threadIdx.x; i < nb; i += 256) {
        uint4 u = p4[i];
        atomicAdd(&rhist[u.x >> 17], 1);
        atomicAdd(&rhist[u.y >> 17], 1);
        atomicAdd(&rhist[u.z >> 17], 1);
        atomicAdd(&rhist[u.w >> 17], 1);
    }
    if (tl + (int)threadIdx.x < n)
        atomicAdd(&rhist[packed[s + tl + threadIdx.x] >> 17], 1);
    __syncthreads();
    if (threadIdx.x < 64) {
        int c0 = rhist[lane];
        int x0 = c0;
        for (int off = 1; off < 64; off <<= 1) {
            int y0 = __shfl_up(x0, off, 64);
            if (lane >= off) x0 += y0;
        }
        rstart[lane] = x0 - c0;
        rcur[lane] = x0 - c0;
        if (lane == 63) rstart[64] = x0;
    }
    __syncthreads();
    // ---- scatter phase (uint4 body) ----
    for (int i = threadIdx.x; i < nb; i += 256) {
        uint4 u = p4[i];
        sorted[atomicAdd(&rcur[u.x >> 17], 1)] = u.x;
        sorted[atomicAdd(&rcur[u.y >> 17], 1)] = u.y;
        sorted[atomicAdd(&rcur[u.z >> 17], 1)] = u.z;
        sorted[atomicAdd(&rcur[u.w >> 17], 1)] = u.w;
    }
    if (tl + (int)threadIdx.x < n) {
        unsigned int u = packed[s + tl + threadIdx.x];
        sorted[atomicAdd(&rcur[u >> 17], 1)] = u;
    }
    __syncthreads();

    // ---- gather: 16 lanes/edge (1 dword = 4 fp8 ch/lane), 4-deep MLP ----
    const unsigned int* Wt1 = (const unsigned int*)Wt8;  // row = 16 dwords
    int q = lane >> 4;
    int ql = lane & 15;
    float b0 = bias[4 * ql], b1 = bias[4 * ql + 1],
          b2 = bias[4 * ql + 2], b3 = bias[4 * ql + 3];

    for (int r = wid; r < BROWS; r += 4) {
        int gr = b * BROWS + r - minv;
        if (gr < 0 || gr >= NUM_NODES) continue;
        int s0 = rstart[r], e0 = rstart[r + 1];
        v2f a01 = {0.0f, 0.0f}, a23 = {0.0f, 0.0f};
        int i = s0 + q;
        for (; i + 12 < e0; i += 16) {  // 4 independent edges in flight
            unsigned int ua = sorted[i], ub = sorted[i + 4];
            unsigned int uc = sorted[i + 8], ud = sorted[i + 12];
            unsigned int wa = Wt1[(size_t)((ua & 0x1FFFFu) << 4) + ql];
            unsigned int wb = Wt1[(size_t)((ub & 0x1FFFFu) << 4) + ql];
            unsigned int wc = Wt1[(size_t)((uc & 0x1FFFFu) << 4) + ql];
            unsigned int wd = Wt1[(size_t)((ud & 0x1FFFFu) << 4) + ql];
#if __has_builtin(__builtin_amdgcn_cvt_pk_f32_fp8)
            a01 += __builtin_amdgcn_cvt_pk_f32_fp8((int)wa, false);
            a23 += __builtin_amdgcn_cvt_pk_f32_fp8((int)wa, true);
            a01 += __builtin_amdgcn_cvt_pk_f32_fp8((int)wb, false);
            a23 += __builtin_amdgcn_cvt_pk_f32_fp8((int)wb, true);
            a01 += __builtin_amdgcn_cvt_pk_f32_fp8((int)wc, false);
            a23 += __builtin_amdgcn_cvt_pk_f32_fp8((int)wc, true);
            a01 += __builtin_amdgcn_cvt_pk_f32_fp8((int)wd, false);
            a23 += __builtin_amdgcn_cvt_pk_f32_fp8((int)wd, true);
#else
            a01.x += fp8_decode_slow(wa & 0xFF) + fp8_decode_slow(wb & 0xFF)
                   + fp8_decode_slow(wc & 0xFF) + fp8_decode_slow(wd & 0xFF);
            a01.y += fp8_decode_slow((wa >> 8) & 0xFF) + fp8_decode_slow((wb >> 8) & 0xFF)
                   + fp8_decode_slow((wc >> 8) & 0xFF) + fp8_decode_slow((wd >> 8) & 0xFF);
            a23.x += fp8_decode_slow((wa >> 16) & 0xFF) + fp8_decode_slow((wb >> 16) & 0xFF)
                   + fp8_decode_slow((wc >> 16) & 0xFF) + fp8_decode_slow((wd >> 16) & 0xFF);
            a23.y += fp8_decode_slow(wa >> 24) + fp8_decode_slow(wb >> 24)
                   + fp8_decode_slow(wc >> 24) + fp8_decode_slow(wd >> 24);
#endif
        }
        for (; i < e0; i += 4) {
            unsigned int w = Wt1[(size_t)((sorted[i] & 0x1FFFFu) << 4) + ql];
#if __has_builtin(__builtin_amdgcn_cvt_pk_f32_fp8)
            a01 += __builtin_amdgcn_cvt_pk_f32_fp8((int)w, false);
            a23 += __builtin_amdgcn_cvt_pk_f32_fp8((int)w, true);
#else
            a01.x += fp8_decode_slow(w & 0xFF);
            a01.y += fp8_decode_slow((w >> 8) & 0xFF);
            a23.x += fp8_decode_slow((w >> 16) & 0xFF);
            a23.y += fp8_decode_slow(w >> 24);
#endif
        }
        float a0 = a01.x, a1 = a01.y, a2 = a23.x, a3 = a23.y;
        a0 += __shfl_xor(a0, 32, 64); a1 += __shfl_xor(a1, 32, 64);
        a2 += __shfl_xor(a2, 32, 64); a3 += __shfl_xor(a3, 32, 64);
        a0 += __shfl_xor(a0, 16, 64); a1 += __shfl_xor(a1, 16, 64);
        a2 += __shfl_xor(a2, 16, 64); a3 += __shfl_xor(a3, 16, 64);

        float x0 = a0 * FP8_INV + b0, x1 = a1 * FP8_INV + b1;
        float x2 = a2 * FP8_INV + b2, x3 = a3 * FP8_INV + b3;
        float m = fmaxf(fmaxf(x0, x1), fmaxf(x2, x3));
        for (int off = 8; off > 0; off >>= 1) m = fmaxf(m, __shfl_xor(m, off, 64));
        float ssum = __expf(x0 - m) + __expf(x1 - m) + __expf(x2 - m) + __expf(x3 - m);
        for (int off = 8; off > 0; off >>= 1) ssum += __shfl_xor(ssum, off, 64);
        float l = m + __logf(ssum);
        if (lane < 16) {
            float4 o = {x0 - l, x1 - l, x2 - l, x3 - l};
            *(float4*)&out[(size_t)gr * OUT_CH + 4 * ql] = o;
        }
    }
}

// ---------- fallback (round-1 path, direct W) ----------
__global__ void LINK_62689342652831_minf_kernel(const int* __restrict__ rows, int n,
                                                int* __restrict__ minp) {
    int tid = blockIdx.x * blockDim.x + threadIdx.x;
    int stride = gridDim.x * blockDim.x;
    int m = INT_MAX;
    for (int i = tid; i < n; i += stride) m = min(m, rows[i]);
    for (int off = 32; off > 0; off >>= 1) m = min(m, __shfl_xor(m, off, 64));
    if ((threadIdx.x & 63) == 0) atomicMin(minp, m);
}

__global__ void LINK_62689342652831_scatter_kernel(const int* __restrict__ rows,
                                                   const int* __restrict__ cols,
                                                   const float* __restrict__ W,
                                                   const int* __restrict__ minp,
                                                   float* __restrict__ out) {
    int lane = threadIdx.x & 63;
    int gw = (blockIdx.x * blockDim.x + threadIdx.x) >> 6;
    int nw = (gridDim.x * blockDim.x) >> 6;
    int minv = *minp;
    for (int e = gw; e < NUM_EDGES; e += nw) {
        int r = rows[e] - minv;
        int c = cols[e];
        float v = W[(size_t)lane * NUM_NODES + c];
        unsafeAtomicAdd(&out[(size_t)r * 64 + lane], v);
    }
}

__global__ void LINK_62689342652831_logsoftmax_kernel(float* __restrict__ out,
                                                      const float* __restrict__ bias) {
    int lane = threadIdx.x & 63;
    int gw = (blockIdx.x * blockDim.x + threadIdx.x) >> 6;
    int nw = (gridDim.x * blockDim.x) >> 6;
    float b = bias[lane];
    for (int r = gw; r < NUM_NODES; r += nw) {
        float x = out[(size_t)r * 64 + lane] + b;
        float m = x;
        for (int off = 32; off > 0; off >>= 1) m = fmaxf(m, __shfl_xor(m, off, 64));
        float e = expf(x - m);
        float s = e;
        for (int off = 32; off > 0; off >>= 1) s += __shfl_xor(s, off, 64);
        out[(size_t)r * 64 + lane] = x - m - logf(s);
    }
}

extern "C" void kernel_launch(void* const* d_in, const int* in_sizes, int n_in,
                              void* d_out, int out_size, void* d_ws, size_t ws_size,
                              hipStream_t stream) {
    const int* edges = (const int*)d_in[0];
    const int* rows = edges;
    const int* cols = edges + NUM_EDGES;
    const float* W = (const float*)d_in[1];
    const float* bias = (const float*)d_in[2];
    float* out = (float*)d_out;

    // workspace layout
    char* ws = (char*)d_ws;
    const size_t OFF_MIN = 0;                                  // 4 B
    const size_t OFF_GCUR = 1024;                              // NBUCK*4 = 6252 B
    const size_t OFF_CBASE = 16384;                            // 256*1563*4 = 1600512 B
    const size_t OFF_PACKED = 2 * 1024 * 1024;                 // NBUCK*CAP*4 = 25.6 MB
    const size_t OFF_WT8 = OFF_PACKED + (size_t)NBUCK * CAP * 4;
    const size_t need = OFF_WT8 + (size_t)NUM_NODES * OUT_CH;

    int* minp = (int*)(ws + OFF_MIN);
    int* gcur = (int*)(ws + OFF_GCUR);
    int* cbase = (int*)(ws + OFF_CBASE);
    unsigned int* packed = (unsigned int*)(ws + OFF_PACKED);
    unsigned char* Wt8 = (unsigned char*)(ws + OFF_WT8);

    if (ws_size >= need) {
        LINK_62689342652831_init_kernel<<<8, 256, 0, stream>>>(minp, gcur);
        LINK_62689342652831_mth_kernel<<<NTRANS + NPBLK, 512, 0, stream>>>(W, Wt8, rows,
                                                                           minp, gcur, cbase);
        LINK_62689342652831_part_kernel<<<NPBLK, 512, 0, stream>>>(rows, cols, cbase, packed);
        LINK_62689342652831_spmm_kernel<<<NBUCK_EXT, 256, 0, stream>>>(packed, gcur, Wt8,
                                                                       bias, minp, out);
    } else {
        hipMemsetAsync(minp, 0x7f, sizeof(int), stream);
        LINK_62689342652831_minf_kernel<<<2048, 256, 0, stream>>>(rows, NUM_EDGES, minp);
        hipMemsetAsync(d_out, 0, (size_t)out_size * sizeof(float), stream);
        LINK_62689342652831_scatter_kernel<<<2048, 256, 0, stream>>>(rows, cols, W, minp, out);
        LINK_62689342652831_logsoftmax_kernel<<<4096, 256, 0, stream>>>(out, bias);
    }
}

// Round 23
// 111.353 us; speedup vs baseline: 1.1508x; 1.0025x over previous
//
#include <hip/hip_runtime.h>
#include <hip/hip_bf16.h>
#include <hip/hip_fp8.h>
#include <limits.h>

#define NUM_NODES 100000
#define OUT_CH 64
#define NUM_EDGES 3200000
#define BROWS 64                     // rows per bucket
#define BSHIFT 6
#define NBUCK 1563                   // ceil(100000/64) raw-row buckets
#define NBUCK_EXT 3125               // spmm grid covers out rows for any minv
#define NPBLK 256                    // edge-pass blocks
#define EPB (NUM_EDGES / NPBLK)      // 12500
#define I4PB (EPB / 4)               // 3125
#define CAP 4096                     // per-bucket region capacity (avg 2046, max~2300)
#define CAPSHIFT 12
#define STAGECAP 4096
#define NTRANS 1563                  // transpose blocks
#define FP8_SCALE 256.0f
#define FP8_INV (1.0f / 256.0f)

typedef float v2f __attribute__((ext_vector_type(2)));

__device__ __forceinline__ float fp8_decode_slow(unsigned b) {
    unsigned s = b >> 7, e = (b >> 3) & 0xF, m = b & 7;
    float v = (e == 0) ? ldexpf((float)m, -9) : ldexpf((float)(8 + m), (int)e - 10);
    return s ? -v : v;
}

// ---------- K0: init (replaces two memsets) ----------
__global__ __launch_bounds__(256) void LINK_62689342652831_init_kernel(
    int* __restrict__ minp, int* __restrict__ gcur) {
    int tid = blockIdx.x * 256 + threadIdx.x;
    if (tid == 0) *minp = INT_MAX;
    for (int i = tid; i < NBUCK; i += gridDim.x * 256) gcur[i] = 0;
}

// ---------- K1: fused [transpose->fp8] || [min + hist + chunk-reserve] ----------
__global__ __launch_bounds__(512) void LINK_62689342652831_mth_kernel(
    const float* __restrict__ W, unsigned char* __restrict__ Wt8,
    const int* __restrict__ rows, int* __restrict__ minp,
    int* __restrict__ gcur, int* __restrict__ cbase) {
    __shared__ float tile[64][65];   // 16640 B
    if (blockIdx.x < NTRANS) {
        int n0 = blockIdx.x * 64;
        int tx = threadIdx.x & 63;
        int ty = threadIdx.x >> 6;   // 0..7
        for (int c = ty; c < 64; c += 8) {
            int n = n0 + tx;
            tile[c][tx] = (n < NUM_NODES) ? W[(size_t)c * NUM_NODES + n] : 0.0f;
        }
        __syncthreads();
        for (int i = ty; i < 64; i += 8) {
            int n = n0 + i;
            if (n < NUM_NODES) {
                __hip_fp8_e4m3 q(FP8_SCALE * tile[tx][i]);
                Wt8[(size_t)n * OUT_CH + tx] = *reinterpret_cast<unsigned char*>(&q);
            }
        }
    } else {
        int blk = blockIdx.x - NTRANS;  // 0..NPBLK-1
        int* h = (int*)tile;            // NBUCK ints
        int* sm = (int*)tile + 2048;    // 8 ints, beyond h
        for (int i = threadIdx.x; i < NBUCK; i += 512) h[i] = 0;
        __syncthreads();
        const int4* r4 = (const int4*)rows;
        int m = INT_MAX;
        for (int i = threadIdx.x; i < I4PB; i += 512) {
            int4 v = r4[blk * I4PB + i];
            m = min(m, min(min(v.x, v.y), min(v.z, v.w)));
            atomicAdd(&h[(unsigned)v.x >> BSHIFT], 1);
            atomicAdd(&h[(unsigned)v.y >> BSHIFT], 1);
            atomicAdd(&h[(unsigned)v.z >> BSHIFT], 1);
            atomicAdd(&h[(unsigned)v.w >> BSHIFT], 1);
        }
        for (int off = 32; off > 0; off >>= 1) m = min(m, __shfl_xor(m, off, 64));
        if ((threadIdx.x & 63) == 0) sm[threadIdx.x >> 6] = m;
        __syncthreads();
        // chunk reservation: one global atomic per non-empty (block,bucket)
        for (int i = threadIdx.x; i < NBUCK; i += 512) {
            int c = h[i];
            if (c) cbase[blk * NBUCK + i] = atomicAdd(&gcur[i], c);
        }
        if (threadIdx.x == 0) {
            int mm = sm[0];
#pragma unroll
            for (int k = 1; k < 8; ++k) mm = min(mm, sm[k]);
            atomicMin(minp, mm);
        }
    }
}

// ---------- K2: partition edges into reserved chunks (LDS cursors) ----------
__global__ __launch_bounds__(512) void LINK_62689342652831_part_kernel(
    const int* __restrict__ rows, const int* __restrict__ cols,
    const int* __restrict__ cbase, unsigned int* __restrict__ packed) {
    __shared__ int offs_l[NBUCK];
    __shared__ int lcur[NBUCK];
    int blk = blockIdx.x;
    for (int i = threadIdx.x; i < NBUCK; i += 512) {
        offs_l[i] = (i << CAPSHIFT) + cbase[blk * NBUCK + i];  // garbage iff bucket empty
        lcur[i] = 0;
    }
    __syncthreads();
    const int4* r4 = (const int4*)rows;
    const int4* c4 = (const int4*)cols;
    for (int i = threadIdx.x; i < I4PB; i += 512) {
        int4 rv = r4[blk * I4PB + i];
        int4 cv = c4[blk * I4PB + i];
#pragma unroll
        for (int k = 0; k < 4; ++k) {
            int r = (k == 0) ? rv.x : (k == 1) ? rv.y : (k == 2) ? rv.z : rv.w;
            int c = (k == 0) ? cv.x : (k == 1) ? cv.y : (k == 2) ? cv.z : cv.w;
            int b = (unsigned)r >> BSHIFT;
            int pos = offs_l[b] + atomicAdd(&lcur[b], 1);
            if (pos < ((b + 1) << CAPSHIFT))  // overflow guard (structurally ~never)
                packed[pos] = ((unsigned)(r & (BROWS - 1)) << 17) | (unsigned)c;
        }
    }
}

// ---------- K3: reg-staged counting-sort + fp8 gather SpMM + log_softmax ----------
__global__ __launch_bounds__(256) void LINK_62689342652831_spmm_kernel(
    const unsigned int* __restrict__ packed, const int* __restrict__ gcur,
    const unsigned char* __restrict__ Wt8, const float* __restrict__ bias,
    const int* __restrict__ minp, float* __restrict__ out) {
    __shared__ unsigned int sorted[STAGECAP];
    __shared__ int rhist[BROWS];
    __shared__ int rstart[BROWS + 1];
    __shared__ int rcur[BROWS];

    int lane = threadIdx.x & 63;
    int wid = threadIdx.x >> 6;  // 0..3
    int b = blockIdx.x;
    int minv = *minp;
    if (b * BROWS - minv >= NUM_NODES) return;
    int s = b << CAPSHIFT;
    int n = 0;
    if (b < NBUCK) n = min(gcur[b], CAP);

    // ---- stage packed into registers ONCE (4x uint4/thread) + hist ----
    int nb = n >> 2;  // whole uint4 count (s is 16B-aligned)
    int tl = nb * 4;
    const uint4* p4 = (const uint4*)(packed + s);
    uint4 pk0 = {0, 0, 0, 0}, pk1 = {0, 0, 0, 0}, pk2 = {0, 0, 0, 0}, pk3 = {0, 0, 0, 0};
    unsigned int pkt = 0;
    int i0 = threadIdx.x, i1 = threadIdx.x + 256,
        i2 = threadIdx.x + 512, i3 = threadIdx.x + 768;
    if (i0 < nb) pk0 = p4[i0];
    if (i1 < nb) pk1 = p4[i1];
    if (i2 < nb) pk2 = p4[i2];
    if (i3 < nb) pk3 = p4[i3];
    bool hastl = (tl + (int)threadIdx.x < n);
    if (hastl) pkt = packed[s + tl + threadIdx.x];

    if (threadIdx.x < BROWS) rhist[threadIdx.x] = 0;
    __syncthreads();
    if (i0 < nb) {
        atomicAdd(&rhist[pk0.x >> 17], 1); atomicAdd(&rhist[pk0.y >> 17], 1);
        atomicAdd(&rhist[pk0.z >> 17], 1); atomicAdd(&rhist[pk0.w >> 17], 1);
    }
    if (i1 < nb) {
        atomicAdd(&rhist[pk1.x >> 17], 1); atomicAdd(&rhist[pk1.y >> 17], 1);
        atomicAdd(&rhist[pk1.z >> 17], 1); atomicAdd(&rhist[pk1.w >> 17], 1);
    }
    if (i2 < nb) {
        atomicAdd(&rhist[pk2.x >> 17], 1); atomicAdd(&rhist[pk2.y >> 17], 1);
        atomicAdd(&rhist[pk2.z >> 17], 1); atomicAdd(&rhist[pk2.w >> 17], 1);
    }
    if (i3 < nb) {
        atomicAdd(&rhist[pk3.x >> 17], 1); atomicAdd(&rhist[pk3.y >> 17], 1);
        atomicAdd(&rhist[pk3.z >> 17], 1); atomicAdd(&rhist[pk3.w >> 17], 1);
    }
    if (hastl) atomicAdd(&rhist[pkt >> 17], 1);
    __syncthreads();
    if (threadIdx.x < 64) {
        int c0 = rhist[lane];
        int x0 = c0;
        for (int off = 1; off < 64; off <<= 1) {
            int y0 = __shfl_up(x0, off, 64);
            if (lane >= off) x0 += y0;
        }
        rstart[lane] = x0 - c0;
        rcur[lane] = x0 - c0;
        if (lane == 63) rstart[64] = x0;
    }
    __syncthreads();
    // ---- scatter from registers (no global reads) ----
    if (i0 < nb) {
        sorted[atomicAdd(&rcur[pk0.x >> 17], 1)] = pk0.x;
        sorted[atomicAdd(&rcur[pk0.y >> 17], 1)] = pk0.y;
        sorted[atomicAdd(&rcur[pk0.z >> 17], 1)] = pk0.z;
        sorted[atomicAdd(&rcur[pk0.w >> 17], 1)] = pk0.w;
    }
    if (i1 < nb) {
        sorted[atomicAdd(&rcur[pk1.x >> 17], 1)] = pk1.x;
        sorted[atomicAdd(&rcur[pk1.y >> 17], 1)] = pk1.y;
        sorted[atomicAdd(&rcur[pk1.z >> 17], 1)] = pk1.z;
        sorted[atomicAdd(&rcur[pk1.w >> 17], 1)] = pk1.w;
    }
    if (i2 < nb) {
        sorted[atomicAdd(&rcur[pk2.x >> 17], 1)] = pk2.x;
        sorted[atomicAdd(&rcur[pk2.y >> 17], 1)] = pk2.y;
        sorted[atomicAdd(&rcur[pk2.z >> 17], 1)] = pk2.z;
        sorted[atomicAdd(&rcur[pk2.w >> 17], 1)] = pk2.w;
    }
    if (i3 < nb) {
        sorted[atomicAdd(&rcur[pk3.x >> 17], 1)] = pk3.x;
        sorted[atomicAdd(&rcur[pk3.y >> 17], 1)] = pk3.y;
        sorted[atomicAdd(&rcur[pk3.z >> 17], 1)] = pk3.z;
        sorted[atomicAdd(&rcur[pk3.w >> 17], 1)] = pk3.w;
    }
    if (hastl) sorted[atomicAdd(&rcur[pkt >> 17], 1)] = pkt;
    __syncthreads();

    // ---- gather: 16 lanes/edge (1 dword = 4 fp8 ch/lane), 4-deep MLP ----
    const unsigned int* Wt1 = (const unsigned int*)Wt8;  // row = 16 dwords
    int q = lane >> 4;
    int ql = lane & 15;
    float b0 = bias[4 * ql], b1 = bias[4 * ql + 1],
          b2 = bias[4 * ql + 2], b3 = bias[4 * ql + 3];

    for (int r = wid; r < BROWS; r += 4) {
        int gr = b * BROWS + r - minv;
        if (gr < 0 || gr >= NUM_NODES) continue;
        int s0 = rstart[r], e0 = rstart[r + 1];
        v2f a01 = {0.0f, 0.0f}, a23 = {0.0f, 0.0f};
        int i = s0 + q;
        for (; i + 12 < e0; i += 16) {  // 4 independent edges in flight
            unsigned int ua = sorted[i], ub = sorted[i + 4];
            unsigned int uc = sorted[i + 8], ud = sorted[i + 12];
            unsigned int wa = Wt1[(size_t)((ua & 0x1FFFFu) << 4) + ql];
            unsigned int wb = Wt1[(size_t)((ub & 0x1FFFFu) << 4) + ql];
            unsigned int wc = Wt1[(size_t)((uc & 0x1FFFFu) << 4) + ql];
            unsigned int wd = Wt1[(size_t)((ud & 0x1FFFFu) << 4) + ql];
#if __has_builtin(__builtin_amdgcn_cvt_pk_f32_fp8)
            a01 += __builtin_amdgcn_cvt_pk_f32_fp8((int)wa, false);
            a23 += __builtin_amdgcn_cvt_pk_f32_fp8((int)wa, true);
            a01 += __builtin_amdgcn_cvt_pk_f32_fp8((int)wb, false);
            a23 += __builtin_amdgcn_cvt_pk_f32_fp8((int)wb, true);
            a01 += __builtin_amdgcn_cvt_pk_f32_fp8((int)wc, false);
            a23 += __builtin_amdgcn_cvt_pk_f32_fp8((int)wc, true);
            a01 += __builtin_amdgcn_cvt_pk_f32_fp8((int)wd, false);
            a23 += __builtin_amdgcn_cvt_pk_f32_fp8((int)wd, true);
#else
            a01.x += fp8_decode_slow(wa & 0xFF) + fp8_decode_slow(wb & 0xFF)
                   + fp8_decode_slow(wc & 0xFF) + fp8_decode_slow(wd & 0xFF);
            a01.y += fp8_decode_slow((wa >> 8) & 0xFF) + fp8_decode_slow((wb >> 8) & 0xFF)
                   + fp8_decode_slow((wc >> 8) & 0xFF) + fp8_decode_slow((wd >> 8) & 0xFF);
            a23.x += fp8_decode_slow((wa >> 16) & 0xFF) + fp8_decode_slow((wb >> 16) & 0xFF)
                   + fp8_decode_slow((wc >> 16) & 0xFF) + fp8_decode_slow((wd >> 16) & 0xFF);
            a23.y += fp8_decode_slow(wa >> 24) + fp8_decode_slow(wb >> 24)
                   + fp8_decode_slow(wc >> 24) + fp8_decode_slow(wd >> 24);
#endif
        }
        for (; i < e0; i += 4) {
            unsigned int w = Wt1[(size_t)((sorted[i] & 0x1FFFFu) << 4) + ql];
#if __has_builtin(__builtin_amdgcn_cvt_pk_f32_fp8)
            a01 += __builtin_amdgcn_cvt_pk_f32_fp8((int)w, false);
            a23 += __builtin_amdgcn_cvt_pk_f32_fp8((int)w, true);
#else
            a01.x += fp8_decode_slow(w & 0xFF);
            a01.y += fp8_decode_slow((w >> 8) & 0xFF);
            a23.x += fp8_decode_slow((w >> 16) & 0xFF);
            a23.y += fp8_decode_slow(w >> 24);
#endif
        }
        float a0 = a01.x, a1 = a01.y, a2 = a23.x, a3 = a23.y;
        a0 += __shfl_xor(a0, 32, 64); a1 += __shfl_xor(a1, 32, 64);
        a2 += __shfl_xor(a2, 32, 64); a3 += __shfl_xor(a3, 32, 64);
        a0 += __shfl_xor(a0, 16, 64); a1 += __shfl_xor(a1, 16, 64);
        a2 += __shfl_xor(a2, 16, 64); a3 += __shfl_xor(a3, 16, 64);

        float x0 = a0 * FP8_INV + b0, x1 = a1 * FP8_INV + b1;
        float x2 = a2 * FP8_INV + b2, x3 = a3 * FP8_INV + b3;
        float m = fmaxf(fmaxf(x0, x1), fmaxf(x2, x3));
        for (int off = 8; off > 0; off >>= 1) m = fmaxf(m, __shfl_xor(m, off, 64));
        float ssum = __expf(x0 - m) + __expf(x1 - m) + __expf(x2 - m) + __expf(x3 - m);
        for (int off = 8; off > 0; off >>= 1) ssum += __shfl_xor(ssum, off, 64);
        float l = m + __logf(ssum);
        if (lane < 16) {
            float4 o = {x0 - l, x1 - l, x2 - l, x3 - l};
            *(float4*)&out[(size_t)gr * OUT_CH + 4 * ql] = o;
        }
    }
}

// ---------- fallback (round-1 path, direct W) ----------
__global__ void LINK_62689342652831_minf_kernel(const int* __restrict__ rows, int n,
                                                int* __restrict__ minp) {
    int tid = blockIdx.x * blockDim.x + threadIdx.x;
    int stride = gridDim.x * blockDim.x;
    int m = INT_MAX;
    for (int i = tid; i < n; i += stride) m = min(m, rows[i]);
    for (int off = 32; off > 0; off >>= 1) m = min(m, __shfl_xor(m, off, 64));
    if ((threadIdx.x & 63) == 0) atomicMin(minp, m);
}

__global__ void LINK_62689342652831_scatter_kernel(const int* __restrict__ rows,
                                                   const int* __restrict__ cols,
                                                   const float* __restrict__ W,
                                                   const int* __restrict__ minp,
                                                   float* __restrict__ out) {
    int lane = threadIdx.x & 63;
    int gw = (blockIdx.x * blockDim.x + threadIdx.x) >> 6;
    int nw = (gridDim.x * blockDim.x) >> 6;
    int minv = *minp;
    for (int e = gw; e < NUM_EDGES; e += nw) {
        int r = rows[e] - minv;
        int c = cols[e];
        float v = W[(size_t)lane * NUM_NODES + c];
        unsafeAtomicAdd(&out[(size_t)r * 64 + lane], v);
    }
}

__global__ void LINK_62689342652831_logsoftmax_kernel(float* __restrict__ out,
                                                      const float* __restrict__ bias) {
    int lane = threadIdx.x & 63;
    int gw = (blockIdx.x * blockDim.x + threadIdx.x) >> 6;
    int nw = (gridDim.x * blockDim.x) >> 6;
    float b = bias[lane];
    for (int r = gw; r < NUM_NODES; r += nw) {
        float x = out[(size_t)r * 64 + lane] + b;
        float m = x;
        for (int off = 32; off > 0; off >>= 1) m = fmaxf(m, __shfl_xor(m, off, 64));
        float e = expf(x - m);
        float s = e;
        for (int off = 32; off > 0; off >>= 1) s += __shfl_xor(s, off, 64);
        out[(size_t)r * 64 + lane] = x - m - logf(s);
    }
}

extern "C" void kernel_launch(void* const* d_in, const int* in_sizes, int n_in,
                              void* d_out, int out_size, void* d_ws, size_t ws_size,
                              hipStream_t stream) {
    const int* edges = (const int*)d_in[0];
    const int* rows = edges;
    const int* cols = edges + NUM_EDGES;
    const float* W = (const float*)d_in[1];
    const float* bias = (const float*)d_in[2];
    float* out = (float*)d_out;

    // workspace layout
    char* ws = (char*)d_ws;
    const size_t OFF_MIN = 0;                                  // 4 B
    const size_t OFF_GCUR = 1024;                              // NBUCK*4 = 6252 B
    const size_t OFF_CBASE = 16384;                            // 256*1563*4 = 1600512 B
    const size_t OFF_PACKED = 2 * 1024 * 1024;                 // NBUCK*CAP*4 = 25.6 MB
    const size_t OFF_WT8 = OFF_PACKED + (size_t)NBUCK * CAP * 4;
    const size_t need = OFF_WT8 + (size_t)NUM_NODES * OUT_CH;

    int* minp = (int*)(ws + OFF_MIN);
    int* gcur = (int*)(ws + OFF_GCUR);
    int* cbase = (int*)(ws + OFF_CBASE);
    unsigned int* packed = (unsigned int*)(ws + OFF_PACKED);
    unsigned char* Wt8 = (unsigned char*)(ws + OFF_WT8);

    if (ws_size >= need) {
        LINK_62689342652831_init_kernel<<<8, 256, 0, stream>>>(minp, gcur);
        LINK_62689342652831_mth_kernel<<<NTRANS + NPBLK, 512, 0, stream>>>(W, Wt8, rows,
                                                                           minp, gcur, cbase);
        LINK_62689342652831_part_kernel<<<NPBLK, 512, 0, stream>>>(rows, cols, cbase, packed);
        LINK_62689342652831_spmm_kernel<<<NBUCK_EXT, 256, 0, stream>>>(packed, gcur, Wt8,
                                                                       bias, minp, out);
    } else {
        hipMemsetAsync(minp, 0x7f, sizeof(int), stream);
        LINK_62689342652831_minf_kernel<<<2048, 256, 0, stream>>>(rows, NUM_EDGES, minp);
        hipMemsetAsync(d_out, 0, (size_t)out_size * sizeof(float), stream);
        LINK_62689342652831_scatter_kernel<<<2048, 256, 0, stream>>>(rows, cols, W, minp, out);
        LINK_62689342652831_logsoftmax_kernel<<<4096, 256, 0, stream>>>(out, bias);
    }
}